// Round 2
// baseline (195.202 us; speedup 1.0000x reference)
//
#include <hip/hip_runtime.h>
#include <hip/hip_bf16.h>

using u16 = unsigned short;
using u32 = unsigned int;

typedef float f32x4 __attribute__((ext_vector_type(4)));
typedef __bf16 bf16x8 __attribute__((ext_vector_type(8)));

constexpr int B_ = 2;
constexpr int S_ = 4096;
constexpr int D_ = 512;
constexpr int H_ = 8;
constexpr int DK_ = 64;
constexpr int M_ = B_ * S_;   // 8192
constexpr int K_ = 512;
constexpr int WHALF = 16;

__device__ __forceinline__ float bf2f(u16 u) {
  return __uint_as_float(((u32)u) << 16);
}
// fp32 -> bf16 round-to-nearest-even (inputs are finite; no NaN handling needed)
__device__ __forceinline__ u16 f2bf(float x) {
  u32 u = __float_as_uint(x);
  u = (u + 0x7fffu + ((u >> 16) & 1u)) >> 16;
  return (u16)u;
}
__device__ __forceinline__ u32 pack2(float a, float b) {
  return (u32)f2bf(a) | ((u32)f2bf(b) << 16);
}

// ---------------------------------------------------------------------------
// GEMM:  C[m][n] = sum_k A[m][k] * W[n][k] + bias[n]   (A: [M,512], W: [512,512])
// A is fp32 (inputs) or bf16 (ctx workspace); W/bias are fp32 (converted to
// bf16 during LDS staging). MODE 0: fp32 out, row-major [M,512].
// MODE 1: bf16 head-split workspace: addr = ((b*H + h)*S + s)*64 + d.
// Tile: BM=128 x BN=64, BK=64. 256 threads = 4 waves (2x2), wave tile 64x32.
// LDS stride 72 elems (144B rows) -> conflict-free b128 read/write.
// ---------------------------------------------------------------------------
template<int MODE, bool A_BF16>
__device__ __forceinline__ void gemm_body(const void* __restrict__ Ap,
                                          const float* __restrict__ W,
                                          const float* __restrict__ bias,
                                          void* __restrict__ Cout)
{
  constexpr int BM = 128, BN = 64, BK = 64, LDT = BK + 8;
  __shared__ u16 As[2][BM * LDT];
  __shared__ u16 Bs[2][BN * LDT];

  const int tid  = threadIdx.x;
  const int lane = tid & 63;
  const int wv   = tid >> 6;
  const int wm   = wv >> 1;   // wave row (0..1) -> 64 rows each
  const int wn   = wv & 1;    // wave col (0..1) -> 32 cols each
  const int m0   = blockIdx.x * BM;
  const int n0   = blockIdx.y * BN;

  const int sc = (tid & 7) * 8;  // staging col (elems)
  const int sr = tid >> 3;       // staging row 0..31

  f32x4 acc[4][2] = {};
  uint4 ra[4], rb[2];

  auto cvt8 = [&](const float* p) -> uint4 {
    const float4 x = *(const float4*)p;
    const float4 y = *(const float4*)(p + 4);
    uint4 r;
    r.x = pack2(x.x, x.y); r.y = pack2(x.z, x.w);
    r.z = pack2(y.x, y.y); r.w = pack2(y.z, y.w);
    return r;
  };

  auto ld = [&](int t) {
    if constexpr (A_BF16) {
      const u16* a = (const u16*)Ap + (size_t)(m0 + sr) * K_ + t * BK + sc;
#pragma unroll
      for (int p = 0; p < 4; ++p) ra[p] = *(const uint4*)(a + (size_t)(p * 32) * K_);
    } else {
      const float* a = (const float*)Ap + (size_t)(m0 + sr) * K_ + t * BK + sc;
#pragma unroll
      for (int p = 0; p < 4; ++p) ra[p] = cvt8(a + (size_t)(p * 32) * K_);
    }
    const float* b = W + (size_t)(n0 + sr) * K_ + t * BK + sc;
#pragma unroll
    for (int p = 0; p < 2; ++p) rb[p] = cvt8(b + (size_t)(p * 32) * K_);
  };
  auto st = [&](int buf) {
#pragma unroll
    for (int p = 0; p < 4; ++p) *(uint4*)&As[buf][(sr + p * 32) * LDT + sc] = ra[p];
#pragma unroll
    for (int p = 0; p < 2; ++p) *(uint4*)&Bs[buf][(sr + p * 32) * LDT + sc] = rb[p];
  };

  ld(0);
  st(0);
  __syncthreads();

  constexpr int NT = K_ / BK;  // 8
#pragma unroll 1
  for (int t = 0; t < NT; ++t) {
    const int cur = t & 1;
    if (t + 1 < NT) ld(t + 1);

    const u16* as = &As[cur][(wm * 64 + (lane & 15)) * LDT + (lane >> 4) * 8];
    const u16* bs = &Bs[cur][(wn * 32 + (lane & 15)) * LDT + (lane >> 4) * 8];
#pragma unroll
    for (int kk = 0; kk < 2; ++kk) {
      bf16x8 af[4], bfr[2];
#pragma unroll
      for (int i = 0; i < 4; ++i) af[i] = *(const bf16x8*)(as + i * 16 * LDT + kk * 32);
#pragma unroll
      for (int j = 0; j < 2; ++j) bfr[j] = *(const bf16x8*)(bs + j * 16 * LDT + kk * 32);
#pragma unroll
      for (int i = 0; i < 4; ++i)
#pragma unroll
        for (int j = 0; j < 2; ++j)
          acc[i][j] = __builtin_amdgcn_mfma_f32_16x16x32_bf16(af[i], bfr[j], acc[i][j], 0, 0, 0);
    }

    if (t + 1 < NT) {
      st(cur ^ 1);
      __syncthreads();
    }
  }

  // epilogue: D frag layout col = lane&15, row = 4*(lane>>4)+r
#pragma unroll
  for (int j = 0; j < 2; ++j) {
    const int col = n0 + wn * 32 + j * 16 + (lane & 15);
    const float bv = bias[col];
#pragma unroll
    for (int i = 0; i < 4; ++i) {
      const int rbase = m0 + wm * 64 + i * 16 + (lane >> 4) * 4;
#pragma unroll
      for (int r = 0; r < 4; ++r) {
        const int row = rbase + r;
        const float vv = acc[i][j][r] + bv;
        if constexpr (MODE == 0) {
          ((float*)Cout)[(size_t)row * D_ + col] = vv;
        } else {
          const int bb = row >> 12;          // / S_
          const int ss = row & (S_ - 1);
          const int hh = col >> 6;           // / DK_
          const int dd = col & (DK_ - 1);
          ((u16*)Cout)[((size_t)(bb * H_ + hh) * S_ + ss) * DK_ + dd] = f2bf(vv);
        }
      }
    }
  }
}

__global__ __launch_bounds__(256) void gemm_qkv(
    const float* __restrict__ q, const float* __restrict__ k, const float* __restrict__ v,
    const float* __restrict__ wq, const float* __restrict__ wk, const float* __restrict__ wv,
    const float* __restrict__ bq, const float* __restrict__ bk, const float* __restrict__ bv,
    u16* __restrict__ Qo, u16* __restrict__ Ko, u16* __restrict__ Vo)
{
  const float* A; const float* W; const float* bias; u16* O;
  if (blockIdx.z == 0)      { A = q; W = wq; bias = bq; O = Qo; }
  else if (blockIdx.z == 1) { A = k; W = wk; bias = bk; O = Ko; }
  else                      { A = v; W = wv; bias = bv; O = Vo; }
  gemm_body<1, false>(A, W, bias, O);
}

__global__ __launch_bounds__(256) void gemm_out(
    const u16* __restrict__ A, const float* __restrict__ W,
    const float* __restrict__ bias, float* __restrict__ C)
{
  gemm_body<0, true>(A, W, bias, C);
}

// ---------------------------------------------------------------------------
// Banded attention: one wave per (b,h,i). Window |i-j| <= 16 -> <= 33 keys.
// QK^T: lanes = 16 j-slots x 4 d-groups(16 each), 2-step shfl reduce.
// Softmax in-register (scores live at lane = slot&15, replicated over groups).
// PV: lane owns d = lane; p broadcast via shfl.
// Output written as ctx[B, S, H*64] (= transpose-merge) for the final GEMM.
// ---------------------------------------------------------------------------
__global__ __launch_bounds__(256) void attn_band(
    const u16* __restrict__ Q, const u16* __restrict__ Kt,
    const u16* __restrict__ Vt, u16* __restrict__ Ctx)
{
  const int lane = threadIdx.x & 63;
  const int wid  = blockIdx.x * 4 + (threadIdx.x >> 6);
  const int i    = wid & (S_ - 1);
  const int bh   = wid >> 12;               // / S_
  const size_t base = (size_t)bh * S_ * DK_;

  const int jlo = (i - WHALF > 0) ? (i - WHALF) : 0;
  const int jhi = (i + WHALF < S_ - 1) ? (i + WHALF) : (S_ - 1);
  const int nj  = jhi - jlo + 1;            // 17..33
  const int nb  = (nj + 15) >> 4;           // 2 or 3 batches of 16 j-slots

  const int jj = lane & 15;                 // j-slot within batch
  const int g  = lane >> 4;                 // d-group (16 d's each)

  // q[16g .. 16g+15] as floats (exact conversion)
  float qv[16];
  {
    const u16* qp = Q + base + (size_t)i * DK_ + g * 16;
    const uint4 q0 = *(const uint4*)qp;
    const uint4 q1 = *(const uint4*)(qp + 8);
    const u32 w[8] = {q0.x, q0.y, q0.z, q0.w, q1.x, q1.y, q1.z, q1.w};
#pragma unroll
    for (int p = 0; p < 8; ++p) {
      qv[2 * p]     = __uint_as_float((w[p] & 0xffffu) << 16);
      qv[2 * p + 1] = __uint_as_float(w[p] & 0xffff0000u);
    }
  }

  float s0 = -INFINITY, s1 = -INFINITY, s2 = -INFINITY;
#pragma unroll
  for (int t = 0; t < 3; ++t) {
    if (t < nb) {
      const int slot = t * 16 + jj;
      int jr = jlo + slot;
      if (jr > jhi) jr = jhi;               // clamp (masked below)
      const u16* kp = Kt + base + (size_t)jr * DK_ + g * 16;
      const uint4 k0 = *(const uint4*)kp;
      const uint4 k1 = *(const uint4*)(kp + 8);
      const u32 w[8] = {k0.x, k0.y, k0.z, k0.w, k1.x, k1.y, k1.z, k1.w};
      float v = 0.f;
#pragma unroll
      for (int p = 0; p < 8; ++p) {
        v += qv[2 * p]     * __uint_as_float((w[p] & 0xffffu) << 16);
        v += qv[2 * p + 1] * __uint_as_float(w[p] & 0xffff0000u);
      }
      v += __shfl_xor(v, 16);
      v += __shfl_xor(v, 32);               // all 4 replicas now hold full dot
      const float sv = (slot < nj) ? v * 0.125f : -INFINITY;
      if (t == 0) s0 = sv; else if (t == 1) s1 = sv; else s2 = sv;
    }
  }

  float mx = fmaxf(fmaxf(s0, s1), s2);
#pragma unroll
  for (int off = 1; off < 16; off <<= 1) mx = fmaxf(mx, __shfl_xor(mx, off));
  float p0 = __expf(s0 - mx);
  float p1 = __expf(s1 - mx);
  float p2 = __expf(s2 - mx);
  float den = p0 + p1 + p2;
#pragma unroll
  for (int off = 1; off < 16; off <<= 1) den += __shfl_xor(den, off);
  const float inv = 1.0f / den;
  p0 *= inv; p1 *= inv; p2 *= inv;

  float ctx = 0.f;
  const u16* vp = Vt + base + lane;
#pragma unroll
  for (int t = 0; t < 3; ++t) {
    if (t < nb) {
      const float pt = (t == 0) ? p0 : (t == 1) ? p1 : p2;
#pragma unroll
      for (int u = 0; u < 16; ++u) {
        const int slot = t * 16 + u;
        if (slot < nj) {
          const float pj = __shfl(pt, u);
          ctx += pj * bf2f(vp[(size_t)(jlo + slot) * DK_]);
        }
      }
    }
  }

  const int bb = bh >> 3;
  const int hh = bh & (H_ - 1);
  Ctx[((size_t)(bb * S_ + i)) * D_ + hh * DK_ + lane] = f2bf(ctx);
}

// ---------------------------------------------------------------------------
extern "C" void kernel_launch(void* const* d_in, const int* in_sizes, int n_in,
                              void* d_out, int out_size, void* d_ws, size_t ws_size,
                              hipStream_t stream)
{
  const float* query = (const float*)d_in[0];
  const float* key   = (const float*)d_in[1];
  const float* value = (const float*)d_in[2];
  const float* wq    = (const float*)d_in[3];
  const float* bq    = (const float*)d_in[4];
  const float* wk    = (const float*)d_in[5];
  const float* bk    = (const float*)d_in[6];
  const float* wv    = (const float*)d_in[7];
  const float* bv    = (const float*)d_in[8];
  const float* wo    = (const float*)d_in[9];
  const float* bo    = (const float*)d_in[10];

  const size_t seg = (size_t)M_ * D_;  // 4M elems, 8MB bf16 each
  u16* Qw = (u16*)d_ws;
  u16* Kw = Qw + seg;
  u16* Vw = Kw + seg;
  u16* Cw = Vw + seg;

  dim3 blk(256);
  // fused Q/K/V projections, head-split bf16 outputs
  gemm_qkv<<<dim3(M_ / 128, D_ / 64, 3), blk, 0, stream>>>(
      query, key, value, wq, wk, wv, bq, bk, bv, Qw, Kw, Vw);
  // banded attention (one wave per query-head row)
  attn_band<<<dim3((B_ * H_ * S_) / 4), blk, 0, stream>>>(Qw, Kw, Vw, Cw);
  // output projection (fp32 out)
  gemm_out<<<dim3(M_ / 128, D_ / 64), blk, 0, stream>>>(Cw, wo, bo, (float*)d_out);
}

// Round 3
// 112.498 us; speedup vs baseline: 1.7352x; 1.7352x over previous
//
#include <hip/hip_runtime.h>
#include <hip/hip_bf16.h>

using u16 = unsigned short;
using u32 = unsigned int;

typedef float f32x4 __attribute__((ext_vector_type(4)));
typedef __bf16 bf16x8 __attribute__((ext_vector_type(8)));

constexpr int B_ = 2;
constexpr int S_ = 4096;
constexpr int D_ = 512;
constexpr int H_ = 8;
constexpr int DK_ = 64;
constexpr int M_ = B_ * S_;   // 8192
constexpr int K_ = 512;

__device__ __forceinline__ float bf2f(u16 u) {
  return __uint_as_float(((u32)u) << 16);
}
// fp32 -> bf16 round-to-nearest-even (inputs finite)
__device__ __forceinline__ u16 f2bf(float x) {
  u32 u = __float_as_uint(x);
  u = (u + 0x7fffu + ((u >> 16) & 1u)) >> 16;
  return (u16)u;
}
__device__ __forceinline__ u32 pack2(float a, float b) {
  return (u32)f2bf(a) | ((u32)f2bf(b) << 16);
}

// ---------------------------------------------------------------------------
// GEMM:  C[m][n] = sum_k A[m][k] * W[n][k] + bias[n]
// MODE 0: fp32 out, row-major [M,512]
// MODE 1: bf16 head-split [bh][s][d]: ((b*H+h)*S + s)*64 + d
// MODE 2: bf16 head-split TRANSPOSED [bh][d][s]: ((b*H+h)*64 + d)*S + s
// Tile BM=128 x BN=64, BK=64, 4 waves (2x2), wave tile 64x32.
// ---------------------------------------------------------------------------
template<int MODE, bool A_BF16>
__device__ __forceinline__ void gemm_body(const void* __restrict__ Ap,
                                          const float* __restrict__ W,
                                          const float* __restrict__ bias,
                                          void* __restrict__ Cout)
{
  constexpr int BM = 128, BN = 64, BK = 64, LDT = BK + 8;
  __shared__ u16 As[2][BM * LDT];
  __shared__ u16 Bs[2][BN * LDT];

  const int tid  = threadIdx.x;
  const int lane = tid & 63;
  const int wv   = tid >> 6;
  const int wm   = wv >> 1;
  const int wn   = wv & 1;
  const int m0   = blockIdx.x * BM;
  const int n0   = blockIdx.y * BN;

  const int sc = (tid & 7) * 8;
  const int sr = tid >> 3;

  f32x4 acc[4][2] = {};
  uint4 ra[4], rb[2];

  auto cvt8 = [&](const float* p) -> uint4 {
    const float4 x = *(const float4*)p;
    const float4 y = *(const float4*)(p + 4);
    uint4 r;
    r.x = pack2(x.x, x.y); r.y = pack2(x.z, x.w);
    r.z = pack2(y.x, y.y); r.w = pack2(y.z, y.w);
    return r;
  };

  auto ld = [&](int t) {
    if constexpr (A_BF16) {
      const u16* a = (const u16*)Ap + (size_t)(m0 + sr) * K_ + t * BK + sc;
#pragma unroll
      for (int p = 0; p < 4; ++p) ra[p] = *(const uint4*)(a + (size_t)(p * 32) * K_);
    } else {
      const float* a = (const float*)Ap + (size_t)(m0 + sr) * K_ + t * BK + sc;
#pragma unroll
      for (int p = 0; p < 4; ++p) ra[p] = cvt8(a + (size_t)(p * 32) * K_);
    }
    const float* b = W + (size_t)(n0 + sr) * K_ + t * BK + sc;
#pragma unroll
    for (int p = 0; p < 2; ++p) rb[p] = cvt8(b + (size_t)(p * 32) * K_);
  };
  auto st = [&](int buf) {
#pragma unroll
    for (int p = 0; p < 4; ++p) *(uint4*)&As[buf][(sr + p * 32) * LDT + sc] = ra[p];
#pragma unroll
    for (int p = 0; p < 2; ++p) *(uint4*)&Bs[buf][(sr + p * 32) * LDT + sc] = rb[p];
  };

  ld(0);
  st(0);
  __syncthreads();

  constexpr int NT = K_ / BK;  // 8
#pragma unroll 1
  for (int t = 0; t < NT; ++t) {
    const int cur = t & 1;
    if (t + 1 < NT) ld(t + 1);

    const u16* as = &As[cur][(wm * 64 + (lane & 15)) * LDT + (lane >> 4) * 8];
    const u16* bs = &Bs[cur][(wn * 32 + (lane & 15)) * LDT + (lane >> 4) * 8];
#pragma unroll
    for (int kk = 0; kk < 2; ++kk) {
      bf16x8 af[4], bfr[2];
#pragma unroll
      for (int i = 0; i < 4; ++i) af[i] = *(const bf16x8*)(as + i * 16 * LDT + kk * 32);
#pragma unroll
      for (int j = 0; j < 2; ++j) bfr[j] = *(const bf16x8*)(bs + j * 16 * LDT + kk * 32);
#pragma unroll
      for (int i = 0; i < 4; ++i)
#pragma unroll
        for (int j = 0; j < 2; ++j)
          acc[i][j] = __builtin_amdgcn_mfma_f32_16x16x32_bf16(af[i], bfr[j], acc[i][j], 0, 0, 0);
    }

    if (t + 1 < NT) {
      st(cur ^ 1);
      __syncthreads();
    }
  }

  // epilogue: D frag layout col(n) = lane&15, row(m) = 4*(lane>>4)+r
#pragma unroll
  for (int j = 0; j < 2; ++j) {
    const int col = n0 + wn * 32 + j * 16 + (lane & 15);
    const float bv = bias[col];
#pragma unroll
    for (int i = 0; i < 4; ++i) {
      const int rbase = m0 + wm * 64 + i * 16 + (lane >> 4) * 4;
      if constexpr (MODE == 2) {
        const int bb = rbase >> 12;
        const int ss = rbase & (S_ - 1);
        const int hh = col >> 6;
        const int dd = col & (DK_ - 1);
        uint2 pk;
        pk.x = pack2(acc[i][j][0] + bv, acc[i][j][1] + bv);
        pk.y = pack2(acc[i][j][2] + bv, acc[i][j][3] + bv);
        *(uint2*)&((u16*)Cout)[((size_t)((bb * H_ + hh) * DK_ + dd)) * S_ + ss] = pk;
      } else {
#pragma unroll
        for (int r = 0; r < 4; ++r) {
          const int row = rbase + r;
          const float vv = acc[i][j][r] + bv;
          if constexpr (MODE == 0) {
            ((float*)Cout)[(size_t)row * D_ + col] = vv;
          } else {
            const int bb = row >> 12;
            const int ss = row & (S_ - 1);
            const int hh = col >> 6;
            const int dd = col & (DK_ - 1);
            ((u16*)Cout)[((size_t)(bb * H_ + hh) * S_ + ss) * DK_ + dd] = f2bf(vv);
          }
        }
      }
    }
  }
}

__global__ __launch_bounds__(256) void gemm_qkv(
    const float* __restrict__ q, const float* __restrict__ k, const float* __restrict__ v,
    const float* __restrict__ wq, const float* __restrict__ wk, const float* __restrict__ wv,
    const float* __restrict__ bq, const float* __restrict__ bk, const float* __restrict__ bv,
    u16* __restrict__ Qo, u16* __restrict__ Ko, u16* __restrict__ Vo)
{
  if (blockIdx.z == 0)      gemm_body<1, false>(q, wq, bq, Qo);
  else if (blockIdx.z == 1) gemm_body<1, false>(k, wk, bk, Ko);
  else                      gemm_body<2, false>(v, wv, bv, Vo);  // V transposed
}

__global__ __launch_bounds__(256) void gemm_out(
    const u16* __restrict__ A, const float* __restrict__ W,
    const float* __restrict__ bias, float* __restrict__ C)
{
  gemm_body<0, true>(A, W, bias, C);
}

// ---------------------------------------------------------------------------
// MFMA banded attention. One wave per 16-query tile; keys span 48 rows
// [q0-16, q0+31] = 3 K-tiles of 16.
// QK^T (swapped): S^T = mfma(A=K_tile, B=Q) -> lane holds q = lane&15,
//   joff = 16t + 4*(lane>>4) + r. Softmax: 12 in-lane + shfl_xor(16,32).
// P (bf16, normalized) -> wave-private LDS [16][72] -> A-frag reads.
// PV: ctx = mfma(A=P, B=Vt) over 2 j-chunks x 4 d-tiles; Vt is [bh][d][s]
//   so B-frag is a contiguous 16B load.
// All OOB j handled by clamp+mask: 16|q0 means every 8-elem chunk is fully
// valid or fully masked (P=0), never partial.
// ---------------------------------------------------------------------------
__global__ __launch_bounds__(256) void attn_band_mfma(
    const u16* __restrict__ Q, const u16* __restrict__ K,
    const u16* __restrict__ Vt, u16* __restrict__ Ctx)
{
  constexpr int LDP = 72;  // 144B rows: 16B-aligned, <=2-way bank aliasing
  __shared__ u16 P_lds[4][16 * LDP];

  const int lane = threadIdx.x & 63;
  const int w    = threadIdx.x >> 6;
  const int wid  = blockIdx.x * 4 + w;
  const int q0   = (wid & 255) << 4;   // 256 q-tiles per (b,h)
  const int bh   = wid >> 8;
  const size_t kbase = (size_t)bh * S_ * DK_;

  u16* pl = &P_lds[w][0];
  const int qr = lane & 15;
  const int g  = lane >> 4;

  // zero P cols 48..63 (the PV K-padding); rows = qr, 4 col-chunks via g
  *(uint2*)&pl[qr * LDP + 48 + 4 * g] = make_uint2(0u, 0u);

  // Q B-frag: lane holds Q[q0+qr][8g + 32kk + i]
  bf16x8 qf[2];
  {
    const u16* qp = Q + kbase + (size_t)(q0 + qr) * DK_ + 8 * g;
    qf[0] = *(const bf16x8*)qp;
    qf[1] = *(const bf16x8*)(qp + 32);
  }

  // QK^T: 3 j-tiles of 16
  f32x4 sc[3];
#pragma unroll
  for (int t = 0; t < 3; ++t) {
    int j = q0 - 16 + 16 * t + qr;          // A-frag row m = qr
    j = min(max(j, 0), S_ - 1);             // clamp; garbage rows fully masked
    const u16* kp = K + kbase + (size_t)j * DK_ + 8 * g;
    const bf16x8 kf0 = *(const bf16x8*)kp;
    const bf16x8 kf1 = *(const bf16x8*)(kp + 32);
    f32x4 a = {};
    a = __builtin_amdgcn_mfma_f32_16x16x32_bf16(kf0, qf[0], a, 0, 0, 0);
    a = __builtin_amdgcn_mfma_f32_16x16x32_bf16(kf1, qf[1], a, 0, 0, 0);
    sc[t] = a;
  }

  // band mask + softmax (q = qr fixed per lane; joff = 16t + 4g + r)
  float s[3][4];
  float mx = -INFINITY;
#pragma unroll
  for (int t = 0; t < 3; ++t)
#pragma unroll
    for (int r = 0; r < 4; ++r) {
      const int joff = 16 * t + 4 * g + r;
      const int j = q0 - 16 + joff;
      const bool ok = (joff >= qr) && (joff <= qr + 32) && (j >= 0) && (j < S_);
      const float v = ok ? sc[t][r] * 0.125f : -INFINITY;
      s[t][r] = v;
      mx = fmaxf(mx, v);
    }
  mx = fmaxf(mx, __shfl_xor(mx, 16));
  mx = fmaxf(mx, __shfl_xor(mx, 32));

  float p[3][4];
  float den = 0.f;
#pragma unroll
  for (int t = 0; t < 3; ++t)
#pragma unroll
    for (int r = 0; r < 4; ++r) {
      p[t][r] = __expf(s[t][r] - mx);
      den += p[t][r];
    }
  den += __shfl_xor(den, 16);
  den += __shfl_xor(den, 32);
  const float inv = 1.0f / den;

  // write normalized bf16 P: row q=qr, cols 16t+4g .. +3
#pragma unroll
  for (int t = 0; t < 3; ++t) {
    uint2 pk;
    pk.x = pack2(p[t][0] * inv, p[t][1] * inv);
    pk.y = pack2(p[t][2] * inv, p[t][3] * inv);
    *(uint2*)&pl[qr * LDP + 16 * t + 4 * g] = pk;
  }

  // PV: ctx[q][d] = sum_joff P[q][joff] * V[j0+joff][d]
  f32x4 cacc[4] = {};
#pragma unroll
  for (int jc = 0; jc < 2; ++jc) {
    const bf16x8 pa = *(const bf16x8*)&pl[qr * LDP + 8 * g + 32 * jc];
#pragma unroll
    for (int nt = 0; nt < 4; ++nt) {
      int jj = q0 - 16 + 8 * g + 32 * jc;   // B-frag k-chunk start
      jj = min(max(jj, 0), S_ - 8);         // chunks never partially OOB
      const u16* vp = Vt + ((size_t)bh * DK_ + 16 * nt + qr) * S_ + jj;
      const bf16x8 vf = *(const bf16x8*)vp;
      cacc[nt] = __builtin_amdgcn_mfma_f32_16x16x32_bf16(pa, vf, cacc[nt], 0, 0, 0);
    }
  }

  // store ctx: lane holds ctx[q = 4g + r][d = 16nt + qr]
  const int bb = bh >> 3;
  const int hh = bh & (H_ - 1);
#pragma unroll
  for (int nt = 0; nt < 4; ++nt)
#pragma unroll
    for (int r = 0; r < 4; ++r) {
      const int qq = 4 * g + r;
      const int dd = 16 * nt + qr;
      Ctx[((size_t)(bb * S_ + q0 + qq)) * D_ + hh * DK_ + dd] = f2bf(cacc[nt][r]);
    }
}

// ---------------------------------------------------------------------------
extern "C" void kernel_launch(void* const* d_in, const int* in_sizes, int n_in,
                              void* d_out, int out_size, void* d_ws, size_t ws_size,
                              hipStream_t stream)
{
  const float* query = (const float*)d_in[0];
  const float* key   = (const float*)d_in[1];
  const float* value = (const float*)d_in[2];
  const float* wq    = (const float*)d_in[3];
  const float* bq    = (const float*)d_in[4];
  const float* wk    = (const float*)d_in[5];
  const float* bk    = (const float*)d_in[6];
  const float* wv    = (const float*)d_in[7];
  const float* bv    = (const float*)d_in[8];
  const float* wo    = (const float*)d_in[9];
  const float* bo    = (const float*)d_in[10];

  const size_t seg = (size_t)M_ * D_;  // 4M elems, 8MB bf16 each
  u16* Qw = (u16*)d_ws;
  u16* Kw = Qw + seg;
  u16* Vw = Kw + seg;   // transposed [bh][d][s]
  u16* Cw = Vw + seg;

  dim3 blk(256);
  gemm_qkv<<<dim3(M_ / 128, D_ / 64, 3), blk, 0, stream>>>(
      query, key, value, wq, wk, wv, bq, bk, bv, Qw, Kw, Vw);
  attn_band_mfma<<<dim3((B_ * H_ * S_) / 64), blk, 0, stream>>>(Qw, Kw, Vw, Cw);
  gemm_out<<<dim3(M_ / 128, D_ / 64), blk, 0, stream>>>(Cw, wo, bo, (float*)d_out);
}

// Round 4
// 80.625 us; speedup vs baseline: 2.4211x; 1.3953x over previous
//
#include <hip/hip_runtime.h>
#include <hip/hip_bf16.h>

using u16 = unsigned short;
using u32 = unsigned int;

typedef float f32x4 __attribute__((ext_vector_type(4)));
typedef __bf16 bf16x8 __attribute__((ext_vector_type(8)));

constexpr int B_ = 2;
constexpr int S_ = 4096;
constexpr int D_ = 512;
constexpr int H_ = 8;
constexpr int DK_ = 64;
constexpr int M_ = B_ * S_;   // 8192
constexpr int K_ = 512;

__device__ __forceinline__ float bf2f(u16 u) {
  return __uint_as_float(((u32)u) << 16);
}
// fp32 -> bf16 round-to-nearest-even (inputs finite)
__device__ __forceinline__ u16 f2bf(float x) {
  u32 u = __float_as_uint(x);
  u = (u + 0x7fffu + ((u >> 16) & 1u)) >> 16;
  return (u16)u;
}
__device__ __forceinline__ u32 pack2(float a, float b) {
  return (u32)f2bf(a) | ((u32)f2bf(b) << 16);
}

// ---------------------------------------------------------------------------
// GEMM:  C[m][n] = sum_k A[m][k] * W[n][k] + bias[n]
// MODE 0: fp32 out, row-major [M,512]
// MODE 1: bf16 head-split [bh][s][d]
// MODE 2: bf16 head-split TRANSPOSED [bh][d][s]
// Tile BM=128 x BN=128, BK=64. 4 waves (2x2), wave tile 64x64.
// Single LDS buffer (36.9 KB, hoisted to kernel scope) + register-prefetch
// double buffering. LDS rows padded to 72 elems (144B) -> b128 at bank floor.
// ---------------------------------------------------------------------------
template<int MODE, bool A_BF16>
__device__ __forceinline__ void gemm_body(const void* __restrict__ Ap,
                                          const float* __restrict__ W,
                                          const float* __restrict__ bias,
                                          void* __restrict__ Cout,
                                          u16* __restrict__ As,
                                          u16* __restrict__ Bs)
{
  constexpr int BM = 128, BN = 128, BK = 64, LDT = BK + 8;

  const int tid  = threadIdx.x;
  const int lane = tid & 63;
  const int wv   = tid >> 6;
  const int wm   = wv >> 1;         // wave row: 64 m each
  const int wn   = wv & 1;          // wave col: 64 n each
  const int m0   = blockIdx.x * BM;
  const int n0   = blockIdx.y * BN;
  const int qr   = lane & 15;
  const int g    = lane >> 4;

  const int sc = (tid & 7) * 8;     // staging col (elems)
  const int sr = tid >> 3;          // staging row 0..31

  f32x4 acc[4][4] = {};
  uint4 ra[4], rb[4];

  auto cvt8 = [&](const float* p) -> uint4 {
    const float4 x = *(const float4*)p;
    const float4 y = *(const float4*)(p + 4);
    uint4 r;
    r.x = pack2(x.x, x.y); r.y = pack2(x.z, x.w);
    r.z = pack2(y.x, y.y); r.w = pack2(y.z, y.w);
    return r;
  };

  auto ld = [&](int t) {
    if constexpr (A_BF16) {
      const u16* a = (const u16*)Ap + (size_t)(m0 + sr) * K_ + t * BK + sc;
#pragma unroll
      for (int p = 0; p < 4; ++p) ra[p] = *(const uint4*)(a + (size_t)(p * 32) * K_);
    } else {
      const float* a = (const float*)Ap + (size_t)(m0 + sr) * K_ + t * BK + sc;
#pragma unroll
      for (int p = 0; p < 4; ++p) ra[p] = cvt8(a + (size_t)(p * 32) * K_);
    }
    const float* b = W + (size_t)(n0 + sr) * K_ + t * BK + sc;
#pragma unroll
    for (int p = 0; p < 4; ++p) rb[p] = cvt8(b + (size_t)(p * 32) * K_);
  };
  auto st = [&]() {
#pragma unroll
    for (int p = 0; p < 4; ++p) *(uint4*)&As[(sr + p * 32) * LDT + sc] = ra[p];
#pragma unroll
    for (int p = 0; p < 4; ++p) *(uint4*)&Bs[(sr + p * 32) * LDT + sc] = rb[p];
  };

  ld(0);
  st();
  __syncthreads();

  const u16* as = &As[(wm * 64 + qr) * LDT + g * 8];
  const u16* bs = &Bs[(wn * 64 + qr) * LDT + g * 8];

  constexpr int NT = K_ / BK;  // 8
#pragma unroll 1
  for (int t = 0; t < NT; ++t) {
    if (t + 1 < NT) ld(t + 1);   // prefetch next tile into registers

#pragma unroll
    for (int kk = 0; kk < 2; ++kk) {
      bf16x8 af[4], bfr[4];
#pragma unroll
      for (int i = 0; i < 4; ++i) af[i]  = *(const bf16x8*)(as + i * 16 * LDT + kk * 32);
#pragma unroll
      for (int j = 0; j < 4; ++j) bfr[j] = *(const bf16x8*)(bs + j * 16 * LDT + kk * 32);
#pragma unroll
      for (int i = 0; i < 4; ++i)
#pragma unroll
        for (int j = 0; j < 4; ++j)
          acc[i][j] = __builtin_amdgcn_mfma_f32_16x16x32_bf16(af[i], bfr[j], acc[i][j], 0, 0, 0);
    }

    if (t + 1 < NT) {
      __syncthreads();           // all waves done reading LDS
      st();
      __syncthreads();           // tile t+1 visible
    }
  }

  // epilogue: D frag layout col(n) = lane&15, row(m) = 4*(lane>>4)+r
#pragma unroll
  for (int j = 0; j < 4; ++j) {
    const int col = n0 + wn * 64 + j * 16 + qr;
    const float bv = bias[col];
#pragma unroll
    for (int i = 0; i < 4; ++i) {
      const int rbase = m0 + wm * 64 + i * 16 + g * 4;
      if constexpr (MODE == 2) {
        const int bb = rbase >> 12;
        const int ss = rbase & (S_ - 1);
        const int hh = col >> 6;
        const int dd = col & (DK_ - 1);
        uint2 pk;
        pk.x = pack2(acc[i][j][0] + bv, acc[i][j][1] + bv);
        pk.y = pack2(acc[i][j][2] + bv, acc[i][j][3] + bv);
        *(uint2*)&((u16*)Cout)[((size_t)((bb * H_ + hh) * DK_ + dd)) * S_ + ss] = pk;
      } else {
#pragma unroll
        for (int r = 0; r < 4; ++r) {
          const int row = rbase + r;
          const float vv = acc[i][j][r] + bv;
          if constexpr (MODE == 0) {
            ((float*)Cout)[(size_t)row * D_ + col] = vv;
          } else {
            const int bb = row >> 12;
            const int ss = row & (S_ - 1);
            const int hh = col >> 6;
            const int dd = col & (DK_ - 1);
            ((u16*)Cout)[((size_t)(bb * H_ + hh) * S_ + ss) * DK_ + dd] = f2bf(vv);
          }
        }
      }
    }
  }
}

__global__ __launch_bounds__(256, 3) void gemm_qkv(
    const float* __restrict__ q, const float* __restrict__ k, const float* __restrict__ v,
    const float* __restrict__ wq, const float* __restrict__ wk, const float* __restrict__ wv,
    const float* __restrict__ bq, const float* __restrict__ bk, const float* __restrict__ bv,
    u16* __restrict__ Qo, u16* __restrict__ Ko, u16* __restrict__ Vo)
{
  __shared__ u16 As[128 * 72];
  __shared__ u16 Bs[128 * 72];
  if (blockIdx.z == 0)      gemm_body<1, false>(q, wq, bq, Qo, As, Bs);
  else if (blockIdx.z == 1) gemm_body<1, false>(k, wk, bk, Ko, As, Bs);
  else                      gemm_body<2, false>(v, wv, bv, Vo, As, Bs);  // V transposed
}

__global__ __launch_bounds__(256, 3) void gemm_out(
    const u16* __restrict__ A, const float* __restrict__ W,
    const float* __restrict__ bias, float* __restrict__ C)
{
  __shared__ u16 As[128 * 72];
  __shared__ u16 Bs[128 * 72];
  gemm_body<0, true>(A, W, bias, C, As, Bs);
}

// ---------------------------------------------------------------------------
// MFMA banded attention (unchanged from round 3). One wave per 16-query tile.
// ---------------------------------------------------------------------------
__global__ __launch_bounds__(256) void attn_band_mfma(
    const u16* __restrict__ Q, const u16* __restrict__ K,
    const u16* __restrict__ Vt, u16* __restrict__ Ctx)
{
  constexpr int LDP = 72;
  __shared__ u16 P_lds[4][16 * LDP];

  const int lane = threadIdx.x & 63;
  const int w    = threadIdx.x >> 6;
  const int wid  = blockIdx.x * 4 + w;
  const int q0   = (wid & 255) << 4;
  const int bh   = wid >> 8;
  const size_t kbase = (size_t)bh * S_ * DK_;

  u16* pl = &P_lds[w][0];
  const int qr = lane & 15;
  const int g  = lane >> 4;

  *(uint2*)&pl[qr * LDP + 48 + 4 * g] = make_uint2(0u, 0u);

  bf16x8 qf[2];
  {
    const u16* qp = Q + kbase + (size_t)(q0 + qr) * DK_ + 8 * g;
    qf[0] = *(const bf16x8*)qp;
    qf[1] = *(const bf16x8*)(qp + 32);
  }

  f32x4 sc[3];
#pragma unroll
  for (int t = 0; t < 3; ++t) {
    int j = q0 - 16 + 16 * t + qr;
    j = min(max(j, 0), S_ - 1);
    const u16* kp = K + kbase + (size_t)j * DK_ + 8 * g;
    const bf16x8 kf0 = *(const bf16x8*)kp;
    const bf16x8 kf1 = *(const bf16x8*)(kp + 32);
    f32x4 a = {};
    a = __builtin_amdgcn_mfma_f32_16x16x32_bf16(kf0, qf[0], a, 0, 0, 0);
    a = __builtin_amdgcn_mfma_f32_16x16x32_bf16(kf1, qf[1], a, 0, 0, 0);
    sc[t] = a;
  }

  float s[3][4];
  float mx = -INFINITY;
#pragma unroll
  for (int t = 0; t < 3; ++t)
#pragma unroll
    for (int r = 0; r < 4; ++r) {
      const int joff = 16 * t + 4 * g + r;
      const int j = q0 - 16 + joff;
      const bool ok = (joff >= qr) && (joff <= qr + 32) && (j >= 0) && (j < S_);
      const float v = ok ? sc[t][r] * 0.125f : -INFINITY;
      s[t][r] = v;
      mx = fmaxf(mx, v);
    }
  mx = fmaxf(mx, __shfl_xor(mx, 16));
  mx = fmaxf(mx, __shfl_xor(mx, 32));

  float p[3][4];
  float den = 0.f;
#pragma unroll
  for (int t = 0; t < 3; ++t)
#pragma unroll
    for (int r = 0; r < 4; ++r) {
      p[t][r] = __expf(s[t][r] - mx);
      den += p[t][r];
    }
  den += __shfl_xor(den, 16);
  den += __shfl_xor(den, 32);
  const float inv = 1.0f / den;

#pragma unroll
  for (int t = 0; t < 3; ++t) {
    uint2 pk;
    pk.x = pack2(p[t][0] * inv, p[t][1] * inv);
    pk.y = pack2(p[t][2] * inv, p[t][3] * inv);
    *(uint2*)&pl[qr * LDP + 16 * t + 4 * g] = pk;
  }

  f32x4 cacc[4] = {};
#pragma unroll
  for (int jc = 0; jc < 2; ++jc) {
    const bf16x8 pa = *(const bf16x8*)&pl[qr * LDP + 8 * g + 32 * jc];
#pragma unroll
    for (int nt = 0; nt < 4; ++nt) {
      int jj = q0 - 16 + 8 * g + 32 * jc;
      jj = min(max(jj, 0), S_ - 8);
      const u16* vp = Vt + ((size_t)bh * DK_ + 16 * nt + qr) * S_ + jj;
      const bf16x8 vf = *(const bf16x8*)vp;
      cacc[nt] = __builtin_amdgcn_mfma_f32_16x16x32_bf16(pa, vf, cacc[nt], 0, 0, 0);
    }
  }

  const int bb = bh >> 3;
  const int hh = bh & (H_ - 1);
#pragma unroll
  for (int nt = 0; nt < 4; ++nt)
#pragma unroll
    for (int r = 0; r < 4; ++r) {
      const int qq = 4 * g + r;
      const int dd = 16 * nt + qr;
      Ctx[((size_t)(bb * S_ + q0 + qq)) * D_ + hh * DK_ + dd] = f2bf(cacc[nt][r]);
    }
}

// ---------------------------------------------------------------------------
extern "C" void kernel_launch(void* const* d_in, const int* in_sizes, int n_in,
                              void* d_out, int out_size, void* d_ws, size_t ws_size,
                              hipStream_t stream)
{
  const float* query = (const float*)d_in[0];
  const float* key   = (const float*)d_in[1];
  const float* value = (const float*)d_in[2];
  const float* wq    = (const float*)d_in[3];
  const float* bq    = (const float*)d_in[4];
  const float* wk    = (const float*)d_in[5];
  const float* bk    = (const float*)d_in[6];
  const float* wv    = (const float*)d_in[7];
  const float* bv    = (const float*)d_in[8];
  const float* wo    = (const float*)d_in[9];
  const float* bo    = (const float*)d_in[10];

  const size_t seg = (size_t)M_ * D_;  // 4M elems, 8MB bf16 each
  u16* Qw = (u16*)d_ws;
  u16* Kw = Qw + seg;
  u16* Vw = Kw + seg;   // transposed [bh][d][s]
  u16* Cw = Vw + seg;

  dim3 blk(256);
  gemm_qkv<<<dim3(M_ / 128, D_ / 128, 3), blk, 0, stream>>>(
      query, key, value, wq, wk, wv, bq, bk, bv, Qw, Kw, Vw);
  attn_band_mfma<<<dim3((B_ * H_ * S_) / 64), blk, 0, stream>>>(Qw, Kw, Vw, Cw);
  gemm_out<<<dim3(M_ / 128, D_ / 128), blk, 0, stream>>>(Cw, wo, bo, (float*)d_out);
}

// Round 5
// 64.425 us; speedup vs baseline: 3.0299x; 1.2515x over previous
//
#include <hip/hip_runtime.h>
#include <hip/hip_bf16.h>

using u16 = unsigned short;
using u32 = unsigned int;

typedef float f32x4 __attribute__((ext_vector_type(4)));
typedef __bf16 bf16x8 __attribute__((ext_vector_type(8)));

constexpr int B_ = 2;
constexpr int S_ = 4096;
constexpr int D_ = 512;
constexpr int H_ = 8;
constexpr int DK_ = 64;
constexpr int M_ = B_ * S_;   // 8192
constexpr int K_ = 512;

__device__ __forceinline__ float bf2f(u16 u) {
  return __uint_as_float(((u32)u) << 16);
}
// fp32 -> bf16 round-to-nearest-even (inputs finite)
__device__ __forceinline__ u16 f2bf(float x) {
  u32 u = __float_as_uint(x);
  u = (u + 0x7fffu + ((u >> 16) & 1u)) >> 16;
  return (u16)u;
}
__device__ __forceinline__ u32 pack2(float a, float b) {
  return (u32)f2bf(a) | ((u32)f2bf(b) << 16);
}

// async global->LDS, 16B per lane; LDS dest = wave-uniform base + lane*16
__device__ __forceinline__ void gload16(const u16* g, u16* l) {
  __builtin_amdgcn_global_load_lds((const __attribute__((address_space(1))) void*)g,
                                   (__attribute__((address_space(3))) void*)l,
                                   16, 0, 0);
}

// ---------------------------------------------------------------------------
// Prepass: convert fp32 inputs/weights to bf16 (once per element, BW-bound).
// q,k,v: 4194304 elems each; wq,wk,wv,wo: 262144 each. 8 elems/thread.
// ---------------------------------------------------------------------------
constexpr int NG_ACT = 3 * (4194304 / 8);   // 1572864 groups
constexpr int NG_W   = 4 * (262144 / 8);    //  131072 groups
constexpr int NG_ALL = NG_ACT + NG_W;       // 1703936

__global__ __launch_bounds__(256) void convert_all(
    const float* __restrict__ q, const float* __restrict__ k, const float* __restrict__ v,
    const float* __restrict__ wq, const float* __restrict__ wk,
    const float* __restrict__ wv, const float* __restrict__ wo,
    u16* __restrict__ qb, u16* __restrict__ kb, u16* __restrict__ vb,
    u16* __restrict__ wqb, u16* __restrict__ wkb, u16* __restrict__ wvb,
    u16* __restrict__ wob)
{
  const int g8 = blockIdx.x * 256 + threadIdx.x;
  if (g8 >= NG_ALL) return;
  const float* s; u16* d; size_t off;
  if (g8 < NG_ACT) {
    const int t = g8 / (4194304 / 8);
    const int r = g8 - t * (4194304 / 8);
    s = (t == 0) ? q : (t == 1) ? k : v;
    d = (t == 0) ? qb : (t == 1) ? kb : vb;
    off = (size_t)r * 8;
  } else {
    const int g2 = g8 - NG_ACT;
    const int t = g2 >> 15;
    const int r = g2 & 32767;
    s = (t == 0) ? wq : (t == 1) ? wk : (t == 2) ? wv : wo;
    d = (t == 0) ? wqb : (t == 1) ? wkb : (t == 2) ? wvb : wob;
    off = (size_t)r * 8;
  }
  const float4 x = *(const float4*)(s + off);
  const float4 y = *(const float4*)(s + off + 4);
  uint4 o;
  o.x = pack2(x.x, x.y); o.y = pack2(x.z, x.w);
  o.z = pack2(y.x, y.y); o.w = pack2(y.z, y.w);
  *(uint4*)(d + off) = o;
}

// ---------------------------------------------------------------------------
// bf16 GEMM:  C[m][n] = sum_k A[m][k] * W[n][k] + bias[n]   (all bf16, K=512)
// MODE 0: fp32 out [M,512]; MODE 1: bf16 head-split [bh][s][d];
// MODE 2: bf16 head-split transposed [bh][d][s].
// Tile 128x128, BK=64, 4 waves (2x2), wave tile 64x64.
// Staging: global_load_lds 16B, double-buffered LDS (2 x 32KB), one barrier
// per K-step. LDS linear 128B rows + XOR swizzle (byte ^= (row&7)<<4) applied
// as inverse-permuted GLOBAL source + swizzled ds_read (T21: both sides).
// ---------------------------------------------------------------------------
template<int MODE>
__device__ __forceinline__ void gemm_body(const u16* __restrict__ A,
                                          const u16* __restrict__ Wt,
                                          const float* __restrict__ bias,
                                          void* __restrict__ Cout,
                                          u16 (*As)[128 * 64], u16 (*Bs)[128 * 64])
{
  const int tid  = threadIdx.x;
  const int lane = tid & 63;
  const int w    = tid >> 6;
  const int wm   = w >> 1;          // wave row: 64 m each
  const int wn   = w & 1;           // wave col: 64 n each
  const int m0   = blockIdx.x * 128;
  const int n0   = blockIdx.y * 128;
  const int qr   = lane & 15;
  const int g    = lane >> 4;

  // staging: per gload16 instr the wave fills 8 rows x 128B linearly;
  // lane i -> row +(i>>3), byte (i&7)*16. Pre-swizzle the SOURCE column:
  const int swz8 = (((lane & 7) ^ (lane >> 3))) * 8;   // elems
  const u16* a0 = A  + (size_t)(m0 + w * 32 + (lane >> 3)) * K_ + swz8;
  const u16* b0 = Wt + (size_t)(n0 + w * 32 + (lane >> 3)) * K_ + swz8;

  auto stage = [&](int buf, int t) {
#pragma unroll
    for (int p = 0; p < 4; ++p)
      gload16(a0 + t * 64 + (size_t)p * 8 * K_, &As[buf][(w * 32 + p * 8) * 64]);
#pragma unroll
    for (int p = 0; p < 4; ++p)
      gload16(b0 + t * 64 + (size_t)p * 8 * K_, &Bs[buf][(w * 32 + p * 8) * 64]);
  };

  f32x4 acc[4][4] = {};

  stage(0, 0);
  __syncthreads();   // drains vmcnt -> tile 0 resident

  const int ax = (qr & 7) << 4;   // row-XOR for swizzled ds_read

  constexpr int NT = K_ / 64;  // 8
#pragma unroll 1
  for (int t = 0; t < NT; ++t) {
    const int buf = t & 1;
    if (t + 1 < NT) stage(buf ^ 1, t + 1);   // prefetch in flight during compute

    const char* ab = (const char*)&As[buf][0] + (wm * 64 + qr) * 128;
    const char* bb = (const char*)&Bs[buf][0] + (wn * 64 + qr) * 128;
#pragma unroll
    for (int kk = 0; kk < 2; ++kk) {
      bf16x8 af[4], bfr[4];
#pragma unroll
      for (int i = 0; i < 4; ++i)
        af[i]  = *(const bf16x8*)(ab + i * 2048 + ((g * 16 + kk * 64) ^ ax));
#pragma unroll
      for (int j = 0; j < 4; ++j)
        bfr[j] = *(const bf16x8*)(bb + j * 2048 + ((g * 16 + kk * 64) ^ ax));
#pragma unroll
      for (int i = 0; i < 4; ++i)
#pragma unroll
        for (int j = 0; j < 4; ++j)
          acc[i][j] = __builtin_amdgcn_mfma_f32_16x16x32_bf16(af[i], bfr[j], acc[i][j], 0, 0, 0);
    }
    __syncthreads();   // waves done reading buf; next-tile loads drained
  }

  // epilogue: D frag layout col(n) = lane&15, row(m) = 4*(lane>>4)+r
#pragma unroll
  for (int j = 0; j < 4; ++j) {
    const int col = n0 + wn * 64 + j * 16 + qr;
    const float bv = bias[col];
#pragma unroll
    for (int i = 0; i < 4; ++i) {
      const int rbase = m0 + wm * 64 + i * 16 + g * 4;
      if constexpr (MODE == 2) {
        const int bb2 = rbase >> 12;
        const int ss = rbase & (S_ - 1);
        const int hh = col >> 6;
        const int dd = col & (DK_ - 1);
        uint2 pk;
        pk.x = pack2(acc[i][j][0] + bv, acc[i][j][1] + bv);
        pk.y = pack2(acc[i][j][2] + bv, acc[i][j][3] + bv);
        *(uint2*)&((u16*)Cout)[((size_t)((bb2 * H_ + hh) * DK_ + dd)) * S_ + ss] = pk;
      } else {
#pragma unroll
        for (int r = 0; r < 4; ++r) {
          const int row = rbase + r;
          const float vv = acc[i][j][r] + bv;
          if constexpr (MODE == 0) {
            ((float*)Cout)[(size_t)row * D_ + col] = vv;
          } else {
            const int bb2 = row >> 12;
            const int ss = row & (S_ - 1);
            const int hh = col >> 6;
            const int dd = col & (DK_ - 1);
            ((u16*)Cout)[((size_t)(bb2 * H_ + hh) * S_ + ss) * DK_ + dd] = f2bf(vv);
          }
        }
      }
    }
  }
}

__global__ __launch_bounds__(256, 2) void gemm_qkv(
    const u16* __restrict__ qb, const u16* __restrict__ kb, const u16* __restrict__ vb,
    const u16* __restrict__ wqb, const u16* __restrict__ wkb, const u16* __restrict__ wvb,
    const float* __restrict__ bq, const float* __restrict__ bk, const float* __restrict__ bv,
    u16* __restrict__ Qo, u16* __restrict__ Ko, u16* __restrict__ Vo)
{
  __shared__ u16 As[2][128 * 64];
  __shared__ u16 Bs[2][128 * 64];
  if (blockIdx.z == 0)      gemm_body<1>(qb, wqb, bq, Qo, As, Bs);
  else if (blockIdx.z == 1) gemm_body<1>(kb, wkb, bk, Ko, As, Bs);
  else                      gemm_body<2>(vb, wvb, bv, Vo, As, Bs);  // V transposed
}

__global__ __launch_bounds__(256, 2) void gemm_out(
    const u16* __restrict__ A, const u16* __restrict__ Wb,
    const float* __restrict__ bias, float* __restrict__ C)
{
  __shared__ u16 As[2][128 * 64];
  __shared__ u16 Bs[2][128 * 64];
  gemm_body<0>(A, Wb, bias, C, As, Bs);
}

// ---------------------------------------------------------------------------
// MFMA banded attention (unchanged from round 3/4). One wave per 16-query tile.
// ---------------------------------------------------------------------------
__global__ __launch_bounds__(256) void attn_band_mfma(
    const u16* __restrict__ Q, const u16* __restrict__ K,
    const u16* __restrict__ Vt, u16* __restrict__ Ctx)
{
  constexpr int LDP = 72;
  __shared__ u16 P_lds[4][16 * LDP];

  const int lane = threadIdx.x & 63;
  const int w    = threadIdx.x >> 6;
  const int wid  = blockIdx.x * 4 + w;
  const int q0   = (wid & 255) << 4;
  const int bh   = wid >> 8;
  const size_t kbase = (size_t)bh * S_ * DK_;

  u16* pl = &P_lds[w][0];
  const int qr = lane & 15;
  const int g  = lane >> 4;

  *(uint2*)&pl[qr * LDP + 48 + 4 * g] = make_uint2(0u, 0u);

  bf16x8 qf[2];
  {
    const u16* qp = Q + kbase + (size_t)(q0 + qr) * DK_ + 8 * g;
    qf[0] = *(const bf16x8*)qp;
    qf[1] = *(const bf16x8*)(qp + 32);
  }

  f32x4 sc[3];
#pragma unroll
  for (int t = 0; t < 3; ++t) {
    int j = q0 - 16 + 16 * t + qr;
    j = min(max(j, 0), S_ - 1);
    const u16* kp = K + kbase + (size_t)j * DK_ + 8 * g;
    const bf16x8 kf0 = *(const bf16x8*)kp;
    const bf16x8 kf1 = *(const bf16x8*)(kp + 32);
    f32x4 a = {};
    a = __builtin_amdgcn_mfma_f32_16x16x32_bf16(kf0, qf[0], a, 0, 0, 0);
    a = __builtin_amdgcn_mfma_f32_16x16x32_bf16(kf1, qf[1], a, 0, 0, 0);
    sc[t] = a;
  }

  float s[3][4];
  float mx = -INFINITY;
#pragma unroll
  for (int t = 0; t < 3; ++t)
#pragma unroll
    for (int r = 0; r < 4; ++r) {
      const int joff = 16 * t + 4 * g + r;
      const int j = q0 - 16 + joff;
      const bool ok = (joff >= qr) && (joff <= qr + 32) && (j >= 0) && (j < S_);
      const float v = ok ? sc[t][r] * 0.125f : -INFINITY;
      s[t][r] = v;
      mx = fmaxf(mx, v);
    }
  mx = fmaxf(mx, __shfl_xor(mx, 16));
  mx = fmaxf(mx, __shfl_xor(mx, 32));

  float p[3][4];
  float den = 0.f;
#pragma unroll
  for (int t = 0; t < 3; ++t)
#pragma unroll
    for (int r = 0; r < 4; ++r) {
      p[t][r] = __expf(s[t][r] - mx);
      den += p[t][r];
    }
  den += __shfl_xor(den, 16);
  den += __shfl_xor(den, 32);
  const float inv = 1.0f / den;

#pragma unroll
  for (int t = 0; t < 3; ++t) {
    uint2 pk;
    pk.x = pack2(p[t][0] * inv, p[t][1] * inv);
    pk.y = pack2(p[t][2] * inv, p[t][3] * inv);
    *(uint2*)&pl[qr * LDP + 16 * t + 4 * g] = pk;
  }

  f32x4 cacc[4] = {};
#pragma unroll
  for (int jc = 0; jc < 2; ++jc) {
    const bf16x8 pa = *(const bf16x8*)&pl[qr * LDP + 8 * g + 32 * jc];
#pragma unroll
    for (int nt = 0; nt < 4; ++nt) {
      int jj = q0 - 16 + 8 * g + 32 * jc;
      jj = min(max(jj, 0), S_ - 8);
      const u16* vp = Vt + ((size_t)bh * DK_ + 16 * nt + qr) * S_ + jj;
      const bf16x8 vf = *(const bf16x8*)vp;
      cacc[nt] = __builtin_amdgcn_mfma_f32_16x16x32_bf16(pa, vf, cacc[nt], 0, 0, 0);
    }
  }

  const int bb = bh >> 3;
  const int hh = bh & (H_ - 1);
#pragma unroll
  for (int nt = 0; nt < 4; ++nt)
#pragma unroll
    for (int r = 0; r < 4; ++r) {
      const int qq = 4 * g + r;
      const int dd = 16 * nt + qr;
      Ctx[((size_t)(bb * S_ + q0 + qq)) * D_ + hh * DK_ + dd] = f2bf(cacc[nt][r]);
    }
}

// ---------------------------------------------------------------------------
extern "C" void kernel_launch(void* const* d_in, const int* in_sizes, int n_in,
                              void* d_out, int out_size, void* d_ws, size_t ws_size,
                              hipStream_t stream)
{
  const float* query = (const float*)d_in[0];
  const float* key   = (const float*)d_in[1];
  const float* value = (const float*)d_in[2];
  const float* wq    = (const float*)d_in[3];
  const float* bq    = (const float*)d_in[4];
  const float* wk    = (const float*)d_in[5];
  const float* bk    = (const float*)d_in[6];
  const float* wv    = (const float*)d_in[7];
  const float* bv    = (const float*)d_in[8];
  const float* wo    = (const float*)d_in[9];
  const float* bo    = (const float*)d_in[10];

  const size_t seg = (size_t)M_ * D_;   // 4M elems (8MB bf16)
  u16* Qw  = (u16*)d_ws;                // [bh][s][d]
  u16* Kw  = Qw + seg;                  // [bh][s][d]
  u16* Vw  = Kw + seg;                  // [bh][d][s] (transposed)
  u16* qb  = Vw + seg;                  // bf16 activations; aliased as Cw after use
  u16* kb  = qb + seg;
  u16* vb  = kb + seg;
  u16* wqb = vb + seg;                  // bf16 weights, 256K elems each
  u16* wkb = wqb + (size_t)D_ * D_;
  u16* wvb = wkb + (size_t)D_ * D_;
  u16* wob = wvb + (size_t)D_ * D_;
  u16* Cw  = qb;                        // ctx reuses qb (dead after gemm_qkv)

  dim3 blk(256);
  convert_all<<<dim3((NG_ALL + 255) / 256), blk, 0, stream>>>(
      query, key, value, wq, wk, wv, wo, qb, kb, vb, wqb, wkb, wvb, wob);
  gemm_qkv<<<dim3(M_ / 128, D_ / 128, 3), blk, 0, stream>>>(
      qb, kb, vb, wqb, wkb, wvb, bq, bk, bv, Qw, Kw, Vw);
  attn_band_mfma<<<dim3((B_ * H_ * S_) / 64), blk, 0, stream>>>(Qw, Kw, Vw, Cw);
  gemm_out<<<dim3(M_ / 128, D_ / 128), blk, 0, stream>>>(Cw, wob, bo, (float*)d_out);
}

// Round 6
// 60.752 us; speedup vs baseline: 3.2131x; 1.0605x over previous
//
#include <hip/hip_runtime.h>
#include <hip/hip_bf16.h>

using u16 = unsigned short;
using u32 = unsigned int;

typedef float f32x4 __attribute__((ext_vector_type(4)));
typedef __bf16 bf16x8 __attribute__((ext_vector_type(8)));

constexpr int B_ = 2;
constexpr int S_ = 4096;
constexpr int D_ = 512;
constexpr int H_ = 8;
constexpr int DK_ = 64;
constexpr int M_ = B_ * S_;   // 8192
constexpr int K_ = 512;

__device__ __forceinline__ float bf2f(u16 u) {
  return __uint_as_float(((u32)u) << 16);
}
// fp32 -> bf16 round-to-nearest-even (inputs finite)
__device__ __forceinline__ u16 f2bf(float x) {
  u32 u = __float_as_uint(x);
  u = (u + 0x7fffu + ((u >> 16) & 1u)) >> 16;
  return (u16)u;
}
__device__ __forceinline__ u32 pack2(float a, float b) {
  return (u32)f2bf(a) | ((u32)f2bf(b) << 16);
}

// async global->LDS, 16B per lane; LDS dest = wave-uniform base + lane*16
__device__ __forceinline__ void gload16(const u16* g, u16* l) {
  __builtin_amdgcn_global_load_lds((const __attribute__((address_space(1))) void*)g,
                                   (__attribute__((address_space(3))) void*)l,
                                   16, 0, 0);
}

// ---------------------------------------------------------------------------
// Prepass: convert fp32 inputs/weights to bf16 (once per element, BW-bound).
// ---------------------------------------------------------------------------
constexpr int NG_ACT = 3 * (4194304 / 8);   // 1572864 groups
constexpr int NG_W   = 4 * (262144 / 8);    //  131072 groups
constexpr int NG_ALL = NG_ACT + NG_W;       // 1703936

__global__ __launch_bounds__(256) void convert_all(
    const float* __restrict__ q, const float* __restrict__ k, const float* __restrict__ v,
    const float* __restrict__ wq, const float* __restrict__ wk,
    const float* __restrict__ wv, const float* __restrict__ wo,
    u16* __restrict__ qb, u16* __restrict__ kb, u16* __restrict__ vb,
    u16* __restrict__ wqb, u16* __restrict__ wkb, u16* __restrict__ wvb,
    u16* __restrict__ wob)
{
  const int g8 = blockIdx.x * 256 + threadIdx.x;
  if (g8 >= NG_ALL) return;
  const float* s; u16* d; size_t off;
  if (g8 < NG_ACT) {
    const int t = g8 / (4194304 / 8);
    const int r = g8 - t * (4194304 / 8);
    s = (t == 0) ? q : (t == 1) ? k : v;
    d = (t == 0) ? qb : (t == 1) ? kb : vb;
    off = (size_t)r * 8;
  } else {
    const int g2 = g8 - NG_ACT;
    const int t = g2 >> 15;
    const int r = g2 & 32767;
    s = (t == 0) ? wq : (t == 1) ? wk : (t == 2) ? wv : wo;
    d = (t == 0) ? wqb : (t == 1) ? wkb : (t == 2) ? wvb : wob;
    off = (size_t)r * 8;
  }
  const float4 x = *(const float4*)(s + off);
  const float4 y = *(const float4*)(s + off + 4);
  uint4 o;
  o.x = pack2(x.x, x.y); o.y = pack2(x.z, x.w);
  o.z = pack2(y.x, y.y); o.w = pack2(y.z, y.w);
  *(uint4*)(d + off) = o;
}

// ---------------------------------------------------------------------------
// bf16 GEMM:  C[m][n] = sum_k A[m][k] * W[n][k] + bias[n]   (all bf16, K=512)
// MODE 0: fp32 out [M,512]; MODE 1: bf16 head-split [bh][s][d];
// MODE 2: bf16 head-split transposed [bh][d][s].
// Tile 128x128, BK=64, 4 waves (2x2), wave tile 64x64.
// SINGLE 32KB LDS buffer + global_load_lds; stage -> barrier -> compute ->
// barrier. Latency hidden by 4 blocks/CU (16 waves) TLP, not per-block
// pipelining. LDS linear 128B rows + XOR swizzle (byte ^= (row&7)<<4) applied
// as inverse-permuted GLOBAL source + swizzled ds_read (T21: both sides).
// ---------------------------------------------------------------------------
template<int MODE>
__device__ __forceinline__ void gemm_body(const u16* __restrict__ A,
                                          const u16* __restrict__ Wt,
                                          const float* __restrict__ bias,
                                          void* __restrict__ Cout,
                                          u16* __restrict__ As,
                                          u16* __restrict__ Bs)
{
  const int tid  = threadIdx.x;
  const int lane = tid & 63;
  const int w    = tid >> 6;
  const int wm   = w >> 1;          // wave row: 64 m each
  const int wn   = w & 1;           // wave col: 64 n each
  const int m0   = blockIdx.x * 128;
  const int n0   = blockIdx.y * 128;
  const int qr   = lane & 15;
  const int g    = lane >> 4;

  // staging: per gload16 instr the wave fills 8 rows x 128B linearly;
  // lane i -> row +(i>>3), byte (i&7)*16. Pre-swizzle the SOURCE column:
  const int swz8 = (((lane & 7) ^ (lane >> 3))) * 8;   // elems
  const u16* a0 = A  + (size_t)(m0 + w * 32 + (lane >> 3)) * K_ + swz8;
  const u16* b0 = Wt + (size_t)(n0 + w * 32 + (lane >> 3)) * K_ + swz8;

  auto stage = [&](int t) {
#pragma unroll
    for (int p = 0; p < 4; ++p)
      gload16(a0 + t * 64 + (size_t)p * 8 * K_, &As[(w * 32 + p * 8) * 64]);
#pragma unroll
    for (int p = 0; p < 4; ++p)
      gload16(b0 + t * 64 + (size_t)p * 8 * K_, &Bs[(w * 32 + p * 8) * 64]);
  };

  f32x4 acc[4][4] = {};

  stage(0);

  const int ax = (qr & 7) << 4;   // row-XOR for swizzled ds_read
  const char* ab = (const char*)As + (wm * 64 + qr) * 128;
  const char* bb = (const char*)Bs + (wn * 64 + qr) * 128;

  constexpr int NT = K_ / 64;  // 8
#pragma unroll 1
  for (int t = 0; t < NT; ++t) {
    __syncthreads();   // stage(t) drained (vmcnt) + visible to all waves

#pragma unroll
    for (int kk = 0; kk < 2; ++kk) {
      bf16x8 af[4], bfr[4];
#pragma unroll
      for (int i = 0; i < 4; ++i)
        af[i]  = *(const bf16x8*)(ab + i * 2048 + ((g * 16 + kk * 64) ^ ax));
#pragma unroll
      for (int j = 0; j < 4; ++j)
        bfr[j] = *(const bf16x8*)(bb + j * 2048 + ((g * 16 + kk * 64) ^ ax));
#pragma unroll
      for (int i = 0; i < 4; ++i)
#pragma unroll
        for (int j = 0; j < 4; ++j)
          acc[i][j] = __builtin_amdgcn_mfma_f32_16x16x32_bf16(af[i], bfr[j], acc[i][j], 0, 0, 0);
    }

    if (t + 1 < NT) {
      __syncthreads();   // all waves done reading buffer
      stage(t + 1);
    }
  }

  // epilogue: D frag layout col(n) = lane&15, row(m) = 4*(lane>>4)+r
#pragma unroll
  for (int j = 0; j < 4; ++j) {
    const int col = n0 + wn * 64 + j * 16 + qr;
    const float bv = bias[col];
#pragma unroll
    for (int i = 0; i < 4; ++i) {
      const int rbase = m0 + wm * 64 + i * 16 + g * 4;
      if constexpr (MODE == 2) {
        const int bb2 = rbase >> 12;
        const int ss = rbase & (S_ - 1);
        const int hh = col >> 6;
        const int dd = col & (DK_ - 1);
        uint2 pk;
        pk.x = pack2(acc[i][j][0] + bv, acc[i][j][1] + bv);
        pk.y = pack2(acc[i][j][2] + bv, acc[i][j][3] + bv);
        *(uint2*)&((u16*)Cout)[((size_t)((bb2 * H_ + hh) * DK_ + dd)) * S_ + ss] = pk;
      } else {
#pragma unroll
        for (int r = 0; r < 4; ++r) {
          const int row = rbase + r;
          const float vv = acc[i][j][r] + bv;
          if constexpr (MODE == 0) {
            ((float*)Cout)[(size_t)row * D_ + col] = vv;
          } else {
            const int bb2 = row >> 12;
            const int ss = row & (S_ - 1);
            const int hh = col >> 6;
            const int dd = col & (DK_ - 1);
            ((u16*)Cout)[((size_t)(bb2 * H_ + hh) * S_ + ss) * DK_ + dd] = f2bf(vv);
          }
        }
      }
    }
  }
}

__global__ __launch_bounds__(256, 4) void gemm_qkv(
    const u16* __restrict__ qb, const u16* __restrict__ kb, const u16* __restrict__ vb,
    const u16* __restrict__ wqb, const u16* __restrict__ wkb, const u16* __restrict__ wvb,
    const float* __restrict__ bq, const float* __restrict__ bk, const float* __restrict__ bv,
    u16* __restrict__ Qo, u16* __restrict__ Ko, u16* __restrict__ Vo)
{
  __shared__ u16 As[128 * 64];
  __shared__ u16 Bs[128 * 64];
  if (blockIdx.z == 0)      gemm_body<1>(qb, wqb, bq, Qo, As, Bs);
  else if (blockIdx.z == 1) gemm_body<1>(kb, wkb, bk, Ko, As, Bs);
  else                      gemm_body<2>(vb, wvb, bv, Vo, As, Bs);  // V transposed
}

__global__ __launch_bounds__(256, 4) void gemm_out(
    const u16* __restrict__ A, const u16* __restrict__ Wb,
    const float* __restrict__ bias, float* __restrict__ C)
{
  __shared__ u16 As[128 * 64];
  __shared__ u16 Bs[128 * 64];
  gemm_body<0>(A, Wb, bias, C, As, Bs);
}

// ---------------------------------------------------------------------------
// MFMA banded attention (unchanged). One wave per 16-query tile.
// ---------------------------------------------------------------------------
__global__ __launch_bounds__(256) void attn_band_mfma(
    const u16* __restrict__ Q, const u16* __restrict__ K,
    const u16* __restrict__ Vt, u16* __restrict__ Ctx)
{
  constexpr int LDP = 72;
  __shared__ u16 P_lds[4][16 * LDP];

  const int lane = threadIdx.x & 63;
  const int w    = threadIdx.x >> 6;
  const int wid  = blockIdx.x * 4 + w;
  const int q0   = (wid & 255) << 4;
  const int bh   = wid >> 8;
  const size_t kbase = (size_t)bh * S_ * DK_;

  u16* pl = &P_lds[w][0];
  const int qr = lane & 15;
  const int g  = lane >> 4;

  *(uint2*)&pl[qr * LDP + 48 + 4 * g] = make_uint2(0u, 0u);

  bf16x8 qf[2];
  {
    const u16* qp = Q + kbase + (size_t)(q0 + qr) * DK_ + 8 * g;
    qf[0] = *(const bf16x8*)qp;
    qf[1] = *(const bf16x8*)(qp + 32);
  }

  f32x4 sc[3];
#pragma unroll
  for (int t = 0; t < 3; ++t) {
    int j = q0 - 16 + 16 * t + qr;
    j = min(max(j, 0), S_ - 1);
    const u16* kp = K + kbase + (size_t)j * DK_ + 8 * g;
    const bf16x8 kf0 = *(const bf16x8*)kp;
    const bf16x8 kf1 = *(const bf16x8*)(kp + 32);
    f32x4 a = {};
    a = __builtin_amdgcn_mfma_f32_16x16x32_bf16(kf0, qf[0], a, 0, 0, 0);
    a = __builtin_amdgcn_mfma_f32_16x16x32_bf16(kf1, qf[1], a, 0, 0, 0);
    sc[t] = a;
  }

  float s[3][4];
  float mx = -INFINITY;
#pragma unroll
  for (int t = 0; t < 3; ++t)
#pragma unroll
    for (int r = 0; r < 4; ++r) {
      const int joff = 16 * t + 4 * g + r;
      const int j = q0 - 16 + joff;
      const bool ok = (joff >= qr) && (joff <= qr + 32) && (j >= 0) && (j < S_);
      const float v = ok ? sc[t][r] * 0.125f : -INFINITY;
      s[t][r] = v;
      mx = fmaxf(mx, v);
    }
  mx = fmaxf(mx, __shfl_xor(mx, 16));
  mx = fmaxf(mx, __shfl_xor(mx, 32));

  float p[3][4];
  float den = 0.f;
#pragma unroll
  for (int t = 0; t < 3; ++t)
#pragma unroll
    for (int r = 0; r < 4; ++r) {
      p[t][r] = __expf(s[t][r] - mx);
      den += p[t][r];
    }
  den += __shfl_xor(den, 16);
  den += __shfl_xor(den, 32);
  const float inv = 1.0f / den;

#pragma unroll
  for (int t = 0; t < 3; ++t) {
    uint2 pk;
    pk.x = pack2(p[t][0] * inv, p[t][1] * inv);
    pk.y = pack2(p[t][2] * inv, p[t][3] * inv);
    *(uint2*)&pl[qr * LDP + 16 * t + 4 * g] = pk;
  }

  f32x4 cacc[4] = {};
#pragma unroll
  for (int jc = 0; jc < 2; ++jc) {
    const bf16x8 pa = *(const bf16x8*)&pl[qr * LDP + 8 * g + 32 * jc];
#pragma unroll
    for (int nt = 0; nt < 4; ++nt) {
      int jj = q0 - 16 + 8 * g + 32 * jc;
      jj = min(max(jj, 0), S_ - 8);
      const u16* vp = Vt + ((size_t)bh * DK_ + 16 * nt + qr) * S_ + jj;
      const bf16x8 vf = *(const bf16x8*)vp;
      cacc[nt] = __builtin_amdgcn_mfma_f32_16x16x32_bf16(pa, vf, cacc[nt], 0, 0, 0);
    }
  }

  const int bb = bh >> 3;
  const int hh = bh & (H_ - 1);
#pragma unroll
  for (int nt = 0; nt < 4; ++nt)
#pragma unroll
    for (int r = 0; r < 4; ++r) {
      const int qq = 4 * g + r;
      const int dd = 16 * nt + qr;
      Ctx[((size_t)(bb * S_ + q0 + qq)) * D_ + hh * DK_ + dd] = f2bf(cacc[nt][r]);
    }
}

// ---------------------------------------------------------------------------
extern "C" void kernel_launch(void* const* d_in, const int* in_sizes, int n_in,
                              void* d_out, int out_size, void* d_ws, size_t ws_size,
                              hipStream_t stream)
{
  const float* query = (const float*)d_in[0];
  const float* key   = (const float*)d_in[1];
  const float* value = (const float*)d_in[2];
  const float* wq    = (const float*)d_in[3];
  const float* bq    = (const float*)d_in[4];
  const float* wk    = (const float*)d_in[5];
  const float* bk    = (const float*)d_in[6];
  const float* wv    = (const float*)d_in[7];
  const float* bv    = (const float*)d_in[8];
  const float* wo    = (const float*)d_in[9];
  const float* bo    = (const float*)d_in[10];

  const size_t seg = (size_t)M_ * D_;   // 4M elems (8MB bf16)
  u16* Qw  = (u16*)d_ws;                // [bh][s][d]
  u16* Kw  = Qw + seg;                  // [bh][s][d]
  u16* Vw  = Kw + seg;                  // [bh][d][s] (transposed)
  u16* qb  = Vw + seg;                  // bf16 activations
  u16* kb  = qb + seg;
  u16* vb  = kb + seg;
  u16* wqb = vb + seg;                  // bf16 weights, 256K elems each
  u16* wkb = wqb + (size_t)D_ * D_;
  u16* wvb = wkb + (size_t)D_ * D_;
  u16* wob = wvb + (size_t)D_ * D_;
  u16* Cw  = qb;                        // ctx reuses qb (dead after gemm_qkv)

  dim3 blk(256);
  convert_all<<<dim3((NG_ALL + 255) / 256), blk, 0, stream>>>(
      query, key, value, wq, wk, wv, wo, qb, kb, vb, wqb, wkb, wvb, wob);
  gemm_qkv<<<dim3(M_ / 128, D_ / 128, 3), blk, 0, stream>>>(
      qb, kb, vb, wqb, wkb, wvb, bq, bk, bv, Qw, Kw, Vw);
  attn_band_mfma<<<dim3((B_ * H_ * S_) / 64), blk, 0, stream>>>(Qw, Kw, Vw, Cw);
  gemm_out<<<dim3(M_ / 128, D_ / 128), blk, 0, stream>>>(Cw, wob, bo, (float*)d_out);
}